// Round 15
// baseline (133.931 us; speedup 1.0000x reference)
//
#include <hip/hip_runtime.h>
#include <stdint.h>

typedef unsigned int u32;
typedef unsigned short u16;
typedef unsigned long long u64;
typedef __bf16 bf16x8 __attribute__((ext_vector_type(8)));
typedef float f32x4 __attribute__((ext_vector_type(4)));
typedef u32 u32x4 __attribute__((ext_vector_type(4)));

#define IN_DIM 512

__device__ __forceinline__ u16 bfr(float f) {
  __bf16 h = (__bf16)f;
  return __builtin_bit_cast(u16, h);
}
__device__ __forceinline__ u16 f2bf(float f) {
  u32 u = __builtin_bit_cast(u32, f);
  u += 0x7fffu + ((u >> 16) & 1u);
  return (u16)(u >> 16);
}
__device__ __forceinline__ u32 pk2(float a, float b) {
  return (u32)f2bf(a) | ((u32)f2bf(b) << 16);
}

// ---------------------------------------------------------------------------
// pack_b: B packed in MFMA-fragment order (unchanged, verified).
// ---------------------------------------------------------------------------
__global__ void pack_b(const float* __restrict__ coeffs,
                       const float* __restrict__ bw,
                       char* __restrict__ Bp) {
  __shared__ float stage[64][56];
  const int tid = threadIdx.x;
  const int q = tid & 3, g = tid >> 2;
  const int id = blockIdx.x * 64 + g;          // (col, s) pair
  const int col = id >> 7, s = id & 127;
  const float* cbase = coeffs + ((size_t)col * IN_DIM + s * 4) * 13;
#pragma unroll
  for (int j = 0; j < 3; ++j) {
    int ch = q + j * 4;
    float4 v = *(const float4*)(cbase + ch * 4);
    stage[g][ch * 4 + 0] = v.x; stage[g][ch * 4 + 1] = v.y;
    stage[g][ch * 4 + 2] = v.z; stage[g][ch * 4 + 3] = v.w;
  }
  if (q == 0) {
    float4 v = *(const float4*)(cbase + 48);
    stage[g][48] = v.x; stage[g][49] = v.y; stage[g][50] = v.z; stage[g][51] = v.w;
  }
  if (q == 1) {
    float4 v = *(const float4*)(bw + (size_t)col * IN_DIM + s * 4);
    stage[g][52] = v.x; stage[g][53] = v.y; stage[g][54] = v.z; stage[g][55] = v.w;
  }
  __syncthreads();
  const int nbp = col >> 7, cb = (col >> 4) & 7, cl = col & 15;
  char* base = Bp + (((size_t)(nbp * 128 + s) * 8 + cb) * 2) * 1024;
#pragma unroll
  for (int r = 0; r < 2; ++r) {
    int idx = q * 2 + r;
    int h = idx & 1;
    int dd = idx >> 1;              // dim-in-step 0..3
    int ks = dd >> 1;
    const float* sf = &stage[g][dd * 13];
    float w = stage[g][52 + dd];
    u16 hh[8];
#pragma unroll
    for (int c = 0; c < 8; ++c) {
      int slot = h * 8 + c;
      float v = slot < 13 ? sf[slot] : (slot < 15 ? w : 0.0f);
      hh[c] = bfr(v);
    }
    u32x4 o;
    o.x = (u32)hh[0] | ((u32)hh[1] << 16);
    o.y = (u32)hh[2] | ((u32)hh[3] << 16);
    o.z = (u32)hh[4] | ((u32)hh[5] << 16);
    o.w = (u32)hh[6] | ((u32)hh[7] << 16);
    int lanei = cl + 16 * (2 * (dd & 1) + h);
    *(u32x4*)(base + (size_t)ks * 1024 + lanei * 16) = o;
  }
}

// ---------------------------------------------------------------------------
// expand_a2: compact A records, 16B per (row, dim) (unchanged, verified):
//   {pk01(b0,b1), pk23(b2,b3), sh|sl<<16, shn|qa<<8}
// ---------------------------------------------------------------------------
__global__ void expand_a2(const float* __restrict__ x, char* __restrict__ Ac) {
  const int tid = threadIdx.x;
  const int lane = tid & 63;
  const int wid = tid >> 6;
  const int b = blockIdx.x;               // 0..16383
  const int rbk = b >> 5;                 // 0..511
  const int dg = (b & 31) * 4 + wid;      // dim-group 0..127
  const int row = rbk * 16 + (lane & 15);
  const int dim = dg * 4 + (lane >> 4);
  float xv = x[(size_t)row * IN_DIM + dim];
  float xc = fminf(fmaxf(xv, -0.9999f), 0.9999f);
  float tp = __fmaf_rn(xc, 2.5f, 3.0f);
  float fj = floorf(tp);
  int jl = (int)fj;  // 0..5
  float u = tp - fj;
  float u2 = u * u, u3 = u2 * u;
  float vv = 1.0f - u;
  float b0 = vv * vv * vv * (1.0f / 6.0f);
  float b3 = u3 * (1.0f / 6.0f);
  float b1 = __fmaf_rn(0.5f, u3, __fmaf_rn(u2, -1.0f, 2.0f / 3.0f));
  float b2 = 1.0f - b0 - b1 - b3;
  float e = __expf(-xv);
  float sg = __fdividef(xv, 1.0f + e);
  u16 sh = bfr(sg);
  float shf = __builtin_bit_cast(float, ((u32)sh) << 16);
  u16 sl = bfr(sg - shf);
  int sstart = jl + 2;                    // 2..7
  u32 qa = (u32)(sstart >> 2);
  u32 shn = (u32)((sstart & 3) << 4);
  u32x4 rec;
  rec.x = (u32)bfr(b0) | ((u32)bfr(b1) << 16);
  rec.y = (u32)bfr(b2) | ((u32)bfr(b3) << 16);
  rec.z = (u32)sh | ((u32)sl << 16);
  rec.w = shn | (qa << 8);
  *(u32x4*)(Ac + ((size_t)(rbk * 512 + dim) * 16 + (lane & 15)) * 16) = rec;
}

// placeFrag: reconstruct 8-slot half from a compact record (verified).
__device__ __forceinline__ u32x4 placeFrag(u32x4 rec, int h) {
  u64 q = (u64)rec.x | ((u64)rec.y << 32);
  u32 shn = rec.w & 0xffu;
  u32 qa = rec.w >> 8;
  u64 lo = q << shn;
  u64 hi = shn ? (q >> (64 - shn)) : 0ull;
  u64 q3 = (u64)rec.z << 16;              // sh<<16 | sl<<32
  u64 fa = h ? (qa ? hi : 0ull) : (qa ? 0ull : lo);
  u64 fb = h ? q3 : (qa ? lo : hi);
  u32x4 r;
  r.x = (u32)fa; r.y = (u32)(fa >> 32);
  r.z = (u32)fb; r.w = (u32)(fb >> 32);
  return r;
}

// ---------------------------------------------------------------------------
// kan_gemm3 v2: barrier-free, LDS-free K-loop; A from compact records.
// Fixes vs R14: (1) XCD-pair B locality restored (nb = xcd>>1, 2MB panel
// L2-resident; same-mb blocks still adjacent within a span of 8 -> L3 dedup
// of A records across nb); (2) depth-2 register pipeline (load S+2 while
// computing S) for both A records and B frags. BM=64, BN=128, grid 512
// (2 blocks/CU, 4 waves/SIMD). Per step: 2 rec + 4 B loads, 2 placeFrag,
// 8 MFMA.
// ---------------------------------------------------------------------------
#define MM2(AF, BV)                                                            \
  {                                                                            \
    __builtin_amdgcn_s_setprio(1);                                             \
    _Pragma("unroll")                                                          \
    for (int fm = 0; fm < 2; ++fm)                                             \
      _Pragma("unroll")                                                        \
      for (int fn = 0; fn < 4; ++fn)                                           \
        acc[fm][fn] = __builtin_amdgcn_mfma_f32_16x16x32_bf16(                 \
            __builtin_bit_cast(bf16x8, AF[fm]),                                \
            __builtin_bit_cast(bf16x8, BV[fn]), acc[fm][fn], 0, 0, 0);         \
    __builtin_amdgcn_s_setprio(0);                                             \
  }

__launch_bounds__(512, 4)
__global__ void kan_gemm3(const float* __restrict__ x,
                          const char* __restrict__ Ac,
                          const char* __restrict__ Bp,
                          float* __restrict__ out) {
  __shared__ __align__(16) char smem[33792];  // epilogue red: 64 x 132 f32

  const int tid = threadIdx.x;
  const int lane = tid & 63;
  const int wid = tid >> 6;
  const int kt = wid >> 2;             // K-split team (sk parity)
  const int wm = (wid >> 1) & 1, wn = wid & 1;
  const int lrow = lane & 15, lkg = lane >> 4;
  const int h = lkg & 1;

  const int s0 = blockIdx.x;
  const int xcd = s0 & 7;
  const int nb = xcd >> 1;                       // B panel pinned to XCD pair
  const int mb = ((s0 >> 3) << 1) | (xcd & 1);   // 0..127; same-mb adjacent

  // A record pointer: rbk = mb*4 + wm*2 + fm, dim = 4s + 2kt + (lkg>>1)
  const char* aptr = Ac +
      ((size_t)((mb * 4 + wm * 2) * 512 + 2 * kt + (lkg >> 1)) * 16 + (lane & 15)) * 16;
  // fm offset = 512*256 = 131072 ; step offset = 4 dims * 256 = 1024
  const char* bptr = Bp + (((size_t)(nb * 128) * 8 + wn * 4) * 2 + kt) * 1024 + (size_t)lane * 16;

  f32x4 acc[2][4];
#pragma unroll
  for (int i = 0; i < 2; ++i)
#pragma unroll
    for (int j = 0; j < 4; ++j) acc[i][j] = (f32x4){0.f, 0.f, 0.f, 0.f};

  u32x4 rA[2], rB[2], bA[4], bB[4];

  // prologue: records/B for steps 0 and 1 (depth-2 pipeline fill)
#pragma unroll
  for (int fm = 0; fm < 2; ++fm)
    rA[fm] = *(const u32x4*)(aptr + fm * 131072);
#pragma unroll
  for (int fm = 0; fm < 2; ++fm)
    rB[fm] = *(const u32x4*)(aptr + 1024 + fm * 131072);
#pragma unroll
  for (int fn = 0; fn < 4; ++fn)
    bA[fn] = *(const u32x4*)(bptr + fn * 2048);
#pragma unroll
  for (int fn = 0; fn < 4; ++fn)
    bB[fn] = *(const u32x4*)(bptr + 16384 + fn * 2048);

  // Step S: place frags from set (loaded at S-2), reload set with S+2,
  // MFMA, then reload B set with S+2 (after MFMA consumes it).
#define STEP3(S, RC, BC)                                                       \
  {                                                                            \
    u32x4 af[2];                                                               \
    af[0] = placeFrag(RC[0], h);                                               \
    af[1] = placeFrag(RC[1], h);                                               \
    int sl_ = (S) + 2 < 128 ? (S) + 2 : 127;                                   \
    const char* ap_ = aptr + (size_t)sl_ * 1024;                               \
    _Pragma("unroll")                                                          \
    for (int fm = 0; fm < 2; ++fm)                                             \
      RC[fm] = *(const u32x4*)(ap_ + fm * 131072);                             \
    MM2(af, BC)                                                                \
    const char* bp_ = bptr + (size_t)sl_ * 16384;                              \
    _Pragma("unroll")                                                          \
    for (int fn = 0; fn < 4; ++fn)                                             \
      BC[fn] = *(const u32x4*)(bp_ + fn * 2048);                               \
  }

#pragma unroll 1
  for (int s = 0; s < 128; s += 2) {
    STEP3(s, rA, bA)
    STEP3(s + 1, rB, bB)
  }

  __syncthreads();  // all waves done; smem safe

  // epilogue: deterministic kt-reduction via LDS (stride 132 floats), +x
  float* red = (float*)smem;
  if (kt == 1) {
#pragma unroll
    for (int fm = 0; fm < 2; ++fm)
#pragma unroll
      for (int fn = 0; fn < 4; ++fn) {
        int rr = wm * 32 + fm * 16 + lkg * 4;
        int cc = wn * 64 + fn * 16 + lrow;
#pragma unroll
        for (int r = 0; r < 4; ++r)
          red[(size_t)(rr + r) * 132 + cc] = acc[fm][fn][r];
      }
  }
  __syncthreads();
  if (kt == 0) {
#pragma unroll
    for (int fm = 0; fm < 2; ++fm)
#pragma unroll
      for (int fn = 0; fn < 4; ++fn) {
        int rr = wm * 32 + fm * 16 + lkg * 4;
        int cc = wn * 64 + fn * 16 + lrow;
        size_t gb = (size_t)(mb * 64 + rr) * IN_DIM + nb * 128 + cc;
#pragma unroll
        for (int r = 0; r < 4; ++r) {
          size_t off = gb + (size_t)r * IN_DIM;
          out[off] = acc[fm][fn][r] + red[(size_t)(rr + r) * 132 + cc] + x[off];
        }
      }
  }
}

// ---------------------------------------------------------------------------
// Mid-tier fallback: R11 interval kernel (89us) — expandA + kan_gemm.
// ---------------------------------------------------------------------------
__device__ __forceinline__ void expandA(float xv, char* rb, u32 swz, u32 k0) {
  float xc = fminf(fmaxf(xv, -0.9999f), 0.9999f);
  float tp = __fmaf_rn(xc, 2.5f, 3.0f);
  float fj = floorf(tp);
  int jl = (int)fj;  // 0..5
  float u = tp - fj;
  float u2 = u * u, u3 = u2 * u;
  float vv = 1.0f - u;
  float b0 = vv * vv * vv * (1.0f / 6.0f);
  float b3 = u3 * (1.0f / 6.0f);
  float b1 = __fmaf_rn(0.5f, u3, __fmaf_rn(u2, -1.0f, 2.0f / 3.0f));
  float b2 = 1.0f - b0 - b1 - b3;
  float e = __expf(-xv);
  float sg = __fdividef(xv, 1.0f + e);
  u16 sh = bfr(sg);
  float shf = __builtin_bit_cast(float, ((u32)sh) << 16);
  u16 sl = bfr(sg - shf);
  u32 pk01 = (u32)bfr(b0) | ((u32)bfr(b1) << 16);
  u32 pk23 = (u32)bfr(b2) | ((u32)bfr(b3) << 16);
  u64 v = (u64)pk01 | (((u64)pk23) << 32);
  int sstart = jl + 2;       // 2..7
  int qa = sstart >> 2;
  int shn = (sstart & 3) << 4;
  u64 lo = v << shn;
  u64 hi = shn ? (v >> (64 - shn)) : 0ull;
  u64 q0 = qa ? 0ull : lo;
  u64 q1 = qa ? lo : hi;
  u64 q2 = qa ? hi : 0ull;
  u64 q3 = (u64)(((u32)sh) << 16) | (((u64)(u32)sl) << 32);
  u32x4 c0, c1;
  c0.x = (u32)q0; c0.y = (u32)(q0 >> 32); c0.z = (u32)q1; c0.w = (u32)(q1 >> 32);
  c1.x = (u32)q2; c1.y = (u32)(q2 >> 32); c1.z = (u32)q3; c1.w = (u32)(q3 >> 32);
  *(u32x4*)(rb + ((k0 ^ swz) << 4)) = c0;
  *(u32x4*)(rb + (((k0 + 1u) ^ swz) << 4)) = c1;
}

#define MM(AF, BV)                                                             \
  {                                                                            \
    __builtin_amdgcn_s_setprio(1);                                             \
    _Pragma("unroll")                                                          \
    for (int fm = 0; fm < 4; ++fm)                                             \
      _Pragma("unroll")                                                        \
      for (int fn = 0; fn < 4; ++fn)                                           \
        acc[fm][fn] = __builtin_amdgcn_mfma_f32_16x16x32_bf16(                 \
            __builtin_bit_cast(bf16x8, AF[fm]),                                \
            __builtin_bit_cast(bf16x8, BV[fn]), acc[fm][fn], 0, 0, 0);         \
    __builtin_amdgcn_s_setprio(0);                                             \
  }

__launch_bounds__(768, 3)
__global__ void kan_gemm(const float* __restrict__ x,
                         const char* __restrict__ Bp,
                         float* __restrict__ out) {
  __shared__ __align__(16) char smem[131072];

  const int tid = threadIdx.x;
  const int lane = tid & 63;
  const int wid = tid >> 6;
  const bool isC = (wid < 8);

  const int kt = wid >> 2;
  const int wm = (wid >> 1) & 1, wn = wid & 1;
  const int lrow = lane & 15, lkg = lane >> 4;

  int s0 = blockIdx.x;
  int xcd = s0 & 7;
  int nb = xcd >> 1;
  int mb = ((s0 >> 3) << 1) | (xcd & 1);

  const int te = tid & 255;
  const int erow = te >> 2;
  const int ad = te & 3;
  const u32 aswz = (u32)(erow & 7);
  const u32 ak0 = (u32)(ad * 2);
  const float* xpa = x + (size_t)(mb * 128 + erow) * IN_DIM + ad;
  const float* xpb = xpa + (size_t)64 * IN_DIM;

  const char* bptr = Bp + (((size_t)(nb * 128) * 8 + wn * 4) * 2 + kt) * 1024 + (size_t)lane * 16;

  f32x4 acc[4][4];
#pragma unroll
  for (int i = 0; i < 4; ++i)
#pragma unroll
    for (int j = 0; j < 4; ++j) acc[i][j] = (f32x4){0.f, 0.f, 0.f, 0.f};

  u32x4 bA[4], bB[4];
  char* ab0 = smem;
  char* ab1 = smem + 65536;

  float xc[8];
#pragma unroll
  for (int j = 0; j < 8; ++j) xc[j] = 0.f;

  if (isC) {
#pragma unroll
    for (int fn = 0; fn < 4; ++fn)
      bA[fn] = *(const u32x4*)(bptr + fn * 2048);
  } else {
    float xi[8];
#pragma unroll
    for (int k = 0; k < 4; ++k) { xi[2 * k] = xpa[4 * k]; xi[2 * k + 1] = xpb[4 * k]; }
#pragma unroll
    for (int k = 0; k < 4; ++k) {
      expandA(xi[2 * k],     ab0 + k * 16384 + erow * 128, aswz, ak0);
      expandA(xi[2 * k + 1], ab0 + k * 16384 + (erow + 64) * 128, aswz, ak0);
    }
#pragma unroll
    for (int k = 0; k < 4; ++k) { xc[2 * k] = xpa[16 + 4 * k]; xc[2 * k + 1] = xpb[16 + 4 * k]; }
  }
  __syncthreads();

  const u32 asl = (((u32)(kt * 4) | (u32)lkg) ^ (u32)(lrow & 7)) << 4;

#pragma unroll 1
  for (int iv = 0; iv < 32; ++iv) {
    if (isC) {
      const char* rbuf = (iv & 1) ? ab1 : ab0;
      const char* arb = rbuf + (wm * 64 + lrow) * 128;
      const int S = iv * 4;
      u32x4 af0[4], af1[4];
#pragma unroll
      for (int fm = 0; fm < 4; ++fm)
        af0[fm] = *(const u32x4*)(arb + fm * 2048 + asl);
#pragma unroll
      for (int fm = 0; fm < 4; ++fm)
        af1[fm] = *(const u32x4*)(arb + 16384 + fm * 2048 + asl);
#pragma unroll
      for (int fn = 0; fn < 4; ++fn)
        bB[fn] = *(const u32x4*)(bptr + (size_t)(S + 1) * 16384 + fn * 2048);
      MM(af0, bA)
#pragma unroll
      for (int fm = 0; fm < 4; ++fm)
        af0[fm] = *(const u32x4*)(arb + 2 * 16384 + fm * 2048 + asl);
#pragma unroll
      for (int fn = 0; fn < 4; ++fn)
        bA[fn] = *(const u32x4*)(bptr + (size_t)(S + 2) * 16384 + fn * 2048);
      MM(af1, bB)
#pragma unroll
      for (int fm = 0; fm < 4; ++fm)
        af1[fm] = *(const u32x4*)(arb + 3 * 16384 + fm * 2048 + asl);
#pragma unroll
      for (int fn = 0; fn < 4; ++fn)
        bB[fn] = *(const u32x4*)(bptr + (size_t)(S + 3) * 16384 + fn * 2048);
      MM(af0, bA)
      {
        int sn = (S + 4 < 128) ? (S + 4) : 127;
#pragma unroll
        for (int fn = 0; fn < 4; ++fn)
          bA[fn] = *(const u32x4*)(bptr + (size_t)sn * 16384 + fn * 2048);
      }
      MM(af1, bB)
    } else {
      if (iv + 1 < 32) {
        char* wb = (iv & 1) ? ab0 : ab1;
#pragma unroll
        for (int k = 0; k < 4; ++k) {
          expandA(xc[2 * k],     wb + k * 16384 + erow * 128, aswz, ak0);
          expandA(xc[2 * k + 1], wb + k * 16384 + (erow + 64) * 128, aswz, ak0);
        }
      }
      {
        int v2 = (iv + 2 < 32) ? (iv + 2) : 31;
        float xn[8];
#pragma unroll
        for (int k = 0; k < 4; ++k) {
          xn[2 * k]     = xpa[v2 * 16 + 4 * k];
          xn[2 * k + 1] = xpb[v2 * 16 + 4 * k];
        }
#pragma unroll
        for (int j = 0; j < 8; ++j) xc[j] = xn[j];
      }
      asm volatile("s_waitcnt lgkmcnt(0)" ::: "memory");
    }
    __builtin_amdgcn_s_barrier();
  }

  __syncthreads();

  float* red = (float*)smem;
  if (isC && kt == 1) {
#pragma unroll
    for (int fm = 0; fm < 4; ++fm)
#pragma unroll
      for (int fn = 0; fn < 4; ++fn) {
        int rr = wm * 64 + fm * 16 + lkg * 4;
        int cc = wn * 64 + fn * 16 + lrow;
#pragma unroll
        for (int r = 0; r < 4; ++r)
          red[(size_t)(rr + r) * 132 + cc] = acc[fm][fn][r];
      }
  }
  __syncthreads();
  if (isC && kt == 0) {
#pragma unroll
    for (int fm = 0; fm < 4; ++fm)
#pragma unroll
      for (int fn = 0; fn < 4; ++fn) {
        int rr = wm * 64 + fm * 16 + lkg * 4;
        int cc = wn * 64 + fn * 16 + lrow;
        size_t gb = (size_t)(mb * 128 + rr) * IN_DIM + nb * 128 + cc;
#pragma unroll
        for (int r = 0; r < 4; ++r) {
          size_t off = gb + (size_t)r * IN_DIM;
          out[off] = acc[fm][fn][r] + red[(size_t)(rr + r) * 132 + cc] + x[off];
        }
      }
  }
}

// ---------------------------------------------------------------------------
// Bottom-tier fallback (round-1 kernel) if ws too small for B_packed (8MB)
// ---------------------------------------------------------------------------
__device__ __forceinline__ void st_b16(char* rb, u32 swz, u32 k0, int c, u16 v) {
  u32 uc = (u32)c;
  u32 byte = (((k0 + (uc >> 3)) ^ swz) << 4) | ((uc & 7u) << 1);
  *(u16*)(rb + byte) = v;
}

__device__ __forceinline__ void stage_a_fb(char* aT, int row, int d, float xv) {
  char* rb = aT + row * 128;
  u32 swz = (u32)(row & 7);
  float xc = fminf(fmaxf(xv, -0.9999f), 0.9999f);
  float tp = __fmaf_rn(xc, 2.5f, 3.0f);
  float fj = floorf(tp);
  int jl = (int)fj;
  float u = tp - fj;
  float u2 = u * u, u3 = u2 * u;
  float vv = 1.0f - u;
  float b0 = vv * vv * vv * (1.0f / 6.0f);
  float b3 = u3 * (1.0f / 6.0f);
  float b1 = __fmaf_rn(0.5f, u3, __fmaf_rn(u2, -1.0f, 2.0f / 3.0f));
  float b2 = 1.0f - b0 - b1 - b3;
  float e = __expf(-xv);
  float sg = __fdividef(xv, 1.0f + e);
  u16 sh = f2bf(sg);
  float shf = __builtin_bit_cast(float, ((u32)sh) << 16);
  u16 slo = f2bf(sg - shf);
  u32 k0 = (u32)d * 2u;
  u32x4 z = {0u, 0u, 0u, 0u};
  *(u32x4*)(rb + ((k0 ^ swz) << 4)) = z;
  u32x4 z2 = {0u, 0u, ((u32)sh) << 16, (u32)slo};
  *(u32x4*)(rb + (((k0 + 1u) ^ swz) << 4)) = z2;
  st_b16(rb, swz, k0, jl + 2, f2bf(b0));
  st_b16(rb, swz, k0, jl + 3, f2bf(b1));
  st_b16(rb, swz, k0, jl + 4, f2bf(b2));
  st_b16(rb, swz, k0, jl + 5, f2bf(b3));
}

__launch_bounds__(512, 2)
__global__ void kan_fused(const float* __restrict__ x,
                          const float* __restrict__ coeffs,
                          const float* __restrict__ bw,
                          float* __restrict__ out) {
  __shared__ __align__(16) char smem[65536];
  const int tid = threadIdx.x;
  const int lane = tid & 63;
  const int wid = tid >> 6;
  const int team = wid >> 2;
  const int wm = (wid >> 1) & 1;
  const int wn = wid & 1;
  const int m0 = wm * 64, n0 = wn * 64;
  const int lrow = lane & 15;
  const int lkg = lane >> 4;
  int s = blockIdx.x;
  int xcd = s & 7;
  int nb = xcd >> 1;
  int mb = (s >> 3) | ((xcd & 1) << 5);
  const int t = tid & 255;
  const int arow = t >> 1;
  const int h = t & 1;
  char* aT = smem + team * 16384;
  char* bT = smem + 32768 + team * 16384;
  const int dim0 = team * 256;
  const float* xptr = x + (size_t)(mb * 128 + arow) * IN_DIM + dim0 + 2 * h;
  const float* cptr = coeffs + ((size_t)((nb * 128 + arow) * IN_DIM) + dim0) * 13 + 26 * h;
  const float* wptr = bw + (size_t)(nb * 128 + arow) * IN_DIM + dim0 + 2 * h;
  f32x4 acc[4][4];
#pragma unroll
  for (int i = 0; i < 4; ++i)
#pragma unroll
    for (int j = 0; j < 4; ++j) acc[i][j] = (f32x4){0.f, 0.f, 0.f, 0.f};
  float2 xv, wv;
  float2 cv0, cv1, cv2, cv3, cv4, cv5, cv6, cv7, cv8, cv9, cv10, cv11, cv12;
#define PREFETCH(STP)                                                     \
  {                                                                       \
    const float* cp_ = cptr + (STP) * 52;                                 \
    xv = *(const float2*)(xptr + (STP) * 4);                              \
    wv = *(const float2*)(wptr + (STP) * 4);                              \
    cv0 = *(const float2*)(cp_ + 0);   cv1 = *(const float2*)(cp_ + 2);   \
    cv2 = *(const float2*)(cp_ + 4);   cv3 = *(const float2*)(cp_ + 6);   \
    cv4 = *(const float2*)(cp_ + 8);   cv5 = *(const float2*)(cp_ + 10);  \
    cv6 = *(const float2*)(cp_ + 12);  cv7 = *(const float2*)(cp_ + 14);  \
    cv8 = *(const float2*)(cp_ + 16);  cv9 = *(const float2*)(cp_ + 18);  \
    cv10 = *(const float2*)(cp_ + 20); cv11 = *(const float2*)(cp_ + 22); \
    cv12 = *(const float2*)(cp_ + 24);                                    \
  }
  PREFETCH(0)
  for (int st = 0; st < 64; ++st) {
    stage_a_fb(aT, arow, 2 * h + 0, xv.x);
    stage_a_fb(aT, arow, 2 * h + 1, xv.y);
    {
      char* rb = bT + arow * 128;
      u32 swz = (u32)(arow & 7);
      u32 k0 = (u32)(2 * h) * 2u;
      u32x4 lo, hi;
      lo.x = pk2(cv0.x, cv0.y); lo.y = pk2(cv1.x, cv1.y);
      lo.z = pk2(cv2.x, cv2.y); lo.w = pk2(cv3.x, cv3.y);
      hi.x = pk2(cv4.x, cv4.y); hi.y = pk2(cv5.x, cv5.y);
      {
        u16 wb = f2bf(wv.x);
        hi.z = (u32)f2bf(cv6.x) | ((u32)wb << 16);
        hi.w = (u32)wb;
      }
      *(u32x4*)(rb + ((k0 ^ swz) << 4)) = lo;
      *(u32x4*)(rb + (((k0 + 1u) ^ swz) << 4)) = hi;
      lo.x = pk2(cv6.y, cv7.x);  lo.y = pk2(cv7.y, cv8.x);
      lo.z = pk2(cv8.y, cv9.x);  lo.w = pk2(cv9.y, cv10.x);
      hi.x = pk2(cv10.y, cv11.x); hi.y = pk2(cv11.y, cv12.x);
      {
        u16 wb = f2bf(wv.y);
        hi.z = (u32)f2bf(cv12.y) | ((u32)wb << 16);
        hi.w = (u32)wb;
      }
      *(u32x4*)(rb + (((k0 + 2u) ^ swz) << 4)) = lo;
      *(u32x4*)(rb + (((k0 + 3u) ^ swz) << 4)) = hi;
    }
    __syncthreads();
    if (st != 63) { PREFETCH(st + 1) }
    {
      const char* arb = aT + (m0 + lrow) * 128;
      const char* brb = bT + (n0 + lrow) * 128;
      u32 rsw = (u32)(lrow & 7);
#pragma unroll
      for (int ks = 0; ks < 2; ++ks) {
        u32 sl2 = (((u32)(ks * 4) | (u32)lkg) ^ rsw) << 4;
        bf16x8 af[4], bfr2[4];
#pragma unroll
        for (int fm = 0; fm < 4; ++fm)
          af[fm] = __builtin_bit_cast(bf16x8, *(const u32x4*)(arb + fm * 2048 + sl2));
#pragma unroll
        for (int fn = 0; fn < 4; ++fn)
          bfr2[fn] = __builtin_bit_cast(bf16x8, *(const u32x4*)(brb + fn * 2048 + sl2));
#pragma unroll
        for (int fm = 0; fm < 4; ++fm)
#pragma unroll
          for (int fn = 0; fn < 4; ++fn)
            acc[fm][fn] = __builtin_amdgcn_mfma_f32_16x16x32_bf16(
                af[fm], bfr2[fn], acc[fm][fn], 0, 0, 0);
      }
    }
    __syncthreads();
  }
  float* red = (float*)smem;
  if (team == 1) {
#pragma unroll
    for (int fm = 0; fm < 4; ++fm)
#pragma unroll
      for (int fn = 0; fn < 4; ++fn) {
        int rr = m0 + fm * 16 + lkg * 4;
        int cc = n0 + fn * 16 + lrow;
#pragma unroll
        for (int r = 0; r < 4; ++r) red[(rr + r) * 128 + cc] = acc[fm][fn][r];
      }
  }
  __syncthreads();
  if (team == 0) {
#pragma unroll
    for (int fm = 0; fm < 4; ++fm)
#pragma unroll
      for (int fn = 0; fn < 4; ++fn) {
        int rr = m0 + fm * 16 + lkg * 4;
        int ccol = n0 + fn * 16 + lrow;
        int grow = mb * 128 + rr;
        int gcol = nb * 128 + ccol;
#pragma unroll
        for (int r = 0; r < 4; ++r) {
          float v = acc[fm][fn][r] + red[(rr + r) * 128 + ccol] +
                    x[(size_t)(grow + r) * IN_DIM + gcol];
          out[(size_t)(grow + r) * IN_DIM + gcol] = v;
        }
      }
  }
}

extern "C" void kernel_launch(void* const* d_in, const int* in_sizes, int n_in,
                              void* d_out, int out_size, void* d_ws, size_t ws_size,
                              hipStream_t stream) {
  const float* x = (const float*)d_in[0];
  const float* coeffs = (const float*)d_in[1];
  const float* bw = (const float*)d_in[2];
  float* out = (float*)d_out;
  const size_t B_BYTES = (size_t)8 << 20;    // 8 MB B_packed
  const size_t A_BYTES = (size_t)64 << 20;   // 64 MB A_compact
  if (ws_size >= B_BYTES + A_BYTES) {
    char* Bp = (char*)d_ws;
    char* Ac = (char*)d_ws + B_BYTES;
    hipLaunchKernelGGL(pack_b, dim3(1024), dim3(256), 0, stream, coeffs, bw, Bp);
    hipLaunchKernelGGL(expand_a2, dim3(16384), dim3(256), 0, stream, x, Ac);
    hipLaunchKernelGGL(kan_gemm3, dim3(512), dim3(512), 0, stream, x, Ac, Bp, out);
  } else if (ws_size >= B_BYTES) {
    char* Bp = (char*)d_ws;
    hipLaunchKernelGGL(pack_b, dim3(1024), dim3(256), 0, stream, coeffs, bw, Bp);
    hipLaunchKernelGGL(kan_gemm, dim3(256), dim3(768), 0, stream, x, Bp, out);
  } else {
    hipLaunchKernelGGL(kan_fused, dim3(256), dim3(512), 0, stream, x, coeffs, bw, out);
  }
}

// Round 16
// 89.321 us; speedup vs baseline: 1.4994x; 1.4994x over previous
//
#include <hip/hip_runtime.h>
#include <stdint.h>

typedef unsigned int u32;
typedef unsigned short u16;
typedef unsigned long long u64;
typedef __bf16 bf16x8 __attribute__((ext_vector_type(8)));
typedef float f32x4 __attribute__((ext_vector_type(4)));
typedef u32 u32x4 __attribute__((ext_vector_type(4)));

#define IN_DIM 512

__device__ __forceinline__ u16 bfr(float f) {
  __bf16 h = (__bf16)f;
  return __builtin_bit_cast(u16, h);
}
__device__ __forceinline__ u16 f2bf(float f) {
  u32 u = __builtin_bit_cast(u32, f);
  u += 0x7fffu + ((u >> 16) & 1u);
  return (u16)(u >> 16);
}
__device__ __forceinline__ u32 pk2(float a, float b) {
  return (u32)f2bf(a) | ((u32)f2bf(b) << 16);
}

// ---------------------------------------------------------------------------
// pack_b: B packed in MFMA-fragment order (L2->VGPR direct in the GEMM).
// Chunk(nbp, s, cb, ks) = 64 lanes x 16B; lane l holds
//   col = nbp*128 + cb*16 + (l&15), kexp = s*64 + ks*32 + (l>>4)*8 .. +7
// Per (col,dim) 16 slots: 0..12 coeffs, 13=W, 14=W, 15=0.
// ---------------------------------------------------------------------------
__global__ void pack_b(const float* __restrict__ coeffs,
                       const float* __restrict__ bw,
                       char* __restrict__ Bp) {
  __shared__ float stage[64][56];
  const int tid = threadIdx.x;
  const int q = tid & 3, g = tid >> 2;
  const int id = blockIdx.x * 64 + g;          // (col, s) pair
  const int col = id >> 7, s = id & 127;
  const float* cbase = coeffs + ((size_t)col * IN_DIM + s * 4) * 13;
#pragma unroll
  for (int j = 0; j < 3; ++j) {
    int ch = q + j * 4;
    float4 v = *(const float4*)(cbase + ch * 4);
    stage[g][ch * 4 + 0] = v.x; stage[g][ch * 4 + 1] = v.y;
    stage[g][ch * 4 + 2] = v.z; stage[g][ch * 4 + 3] = v.w;
  }
  if (q == 0) {
    float4 v = *(const float4*)(cbase + 48);
    stage[g][48] = v.x; stage[g][49] = v.y; stage[g][50] = v.z; stage[g][51] = v.w;
  }
  if (q == 1) {
    float4 v = *(const float4*)(bw + (size_t)col * IN_DIM + s * 4);
    stage[g][52] = v.x; stage[g][53] = v.y; stage[g][54] = v.z; stage[g][55] = v.w;
  }
  __syncthreads();
  const int nbp = col >> 7, cb = (col >> 4) & 7, cl = col & 15;
  char* base = Bp + (((size_t)(nbp * 128 + s) * 8 + cb) * 2) * 1024;
#pragma unroll
  for (int r = 0; r < 2; ++r) {
    int idx = q * 2 + r;
    int h = idx & 1;
    int dd = idx >> 1;              // dim-in-step 0..3
    int ks = dd >> 1;
    const float* sf = &stage[g][dd * 13];
    float w = stage[g][52 + dd];
    u16 hh[8];
#pragma unroll
    for (int c = 0; c < 8; ++c) {
      int slot = h * 8 + c;
      float v = slot < 13 ? sf[slot] : (slot < 15 ? w : 0.0f);
      hh[c] = bfr(v);
    }
    u32x4 o;
    o.x = (u32)hh[0] | ((u32)hh[1] << 16);
    o.y = (u32)hh[2] | ((u32)hh[3] << 16);
    o.z = (u32)hh[4] | ((u32)hh[5] << 16);
    o.w = (u32)hh[6] | ((u32)hh[7] << 16);
    int lanei = cl + 16 * (2 * (dd & 1) + h);
    *(u32x4*)(base + (size_t)ks * 1024 + lanei * 16) = o;
  }
}

// ---------------------------------------------------------------------------
// A expansion: one x -> 16 bf16 K-slots as two swizzled ds_write_b128.
// ---------------------------------------------------------------------------
__device__ __forceinline__ void expandA(float xv, char* rb, u32 swz, u32 k0) {
  float xc = fminf(fmaxf(xv, -0.9999f), 0.9999f);
  float tp = __fmaf_rn(xc, 2.5f, 3.0f);
  float fj = floorf(tp);
  int jl = (int)fj;  // 0..5
  float u = tp - fj;
  float u2 = u * u, u3 = u2 * u;
  float vv = 1.0f - u;
  float b0 = vv * vv * vv * (1.0f / 6.0f);
  float b3 = u3 * (1.0f / 6.0f);
  float b1 = __fmaf_rn(0.5f, u3, __fmaf_rn(u2, -1.0f, 2.0f / 3.0f));
  float b2 = 1.0f - b0 - b1 - b3;
  float e = __expf(-xv);
  float sg = __fdividef(xv, 1.0f + e);
  u16 sh = bfr(sg);
  float shf = __builtin_bit_cast(float, ((u32)sh) << 16);
  u16 sl = bfr(sg - shf);
  u32 pk01 = (u32)bfr(b0) | ((u32)bfr(b1) << 16);
  u32 pk23 = (u32)bfr(b2) | ((u32)bfr(b3) << 16);
  u64 v = (u64)pk01 | (((u64)pk23) << 32);
  int sstart = jl + 2;       // 2..7
  int qa = sstart >> 2;
  int shn = (sstart & 3) << 4;
  u64 lo = v << shn;
  u64 hi = shn ? (v >> (64 - shn)) : 0ull;
  u64 q0 = qa ? 0ull : lo;
  u64 q1 = qa ? lo : hi;
  u64 q2 = qa ? hi : 0ull;
  u64 q3 = (u64)(((u32)sh) << 16) | (((u64)(u32)sl) << 32);
  u32x4 c0, c1;
  c0.x = (u32)q0; c0.y = (u32)(q0 >> 32); c0.z = (u32)q1; c0.w = (u32)(q1 >> 32);
  c1.x = (u32)q2; c1.y = (u32)(q2 >> 32); c1.z = (u32)q3; c1.w = (u32)(q3 >> 32);
  *(u32x4*)(rb + ((k0 ^ swz) << 4)) = c0;
  *(u32x4*)(rb + (((k0 + 1u) ^ swz) << 4)) = c1;
}

// ---------------------------------------------------------------------------
// Main GEMM (best measured: 89.1 us, R11): wave-specialized, 4-STEP SYNC
// INTERVALS (32 lgkm-only barriers). A flows through two 64KB interval
// buffers: expansion (waves 8-11) fills interval i+1 while compute
// (waves 0-7) consumes interval i's 4 steps back-to-back with rolling
// register double-buffers (af0/af1, bA/bB) and NO intra-interval syncs.
// x loads are issued a full interval (~3000cy) ahead of use.
// ---------------------------------------------------------------------------
#define MM(AF, BV)                                                             \
  {                                                                            \
    __builtin_amdgcn_s_setprio(1);                                             \
    _Pragma("unroll")                                                          \
    for (int fm = 0; fm < 4; ++fm)                                             \
      _Pragma("unroll")                                                        \
      for (int fn = 0; fn < 4; ++fn)                                           \
        acc[fm][fn] = __builtin_amdgcn_mfma_f32_16x16x32_bf16(                 \
            __builtin_bit_cast(bf16x8, AF[fm]),                                \
            __builtin_bit_cast(bf16x8, BV[fn]), acc[fm][fn], 0, 0, 0);         \
    __builtin_amdgcn_s_setprio(0);                                             \
  }

__launch_bounds__(768, 3)
__global__ void kan_gemm(const float* __restrict__ x,
                         const char* __restrict__ Bp,
                         float* __restrict__ out) {
  __shared__ __align__(16) char smem[131072];  // 2 x 64KB interval buffers

  const int tid = threadIdx.x;
  const int lane = tid & 63;
  const int wid = tid >> 6;
  const bool isC = (wid < 8);

  const int kt = wid >> 2;             // 0/1 (compute K-split team)
  const int wm = (wid >> 1) & 1, wn = wid & 1;
  const int lrow = lane & 15, lkg = lane >> 4;

  int s0 = blockIdx.x;
  int xcd = s0 & 7;
  int nb = xcd >> 1;                   // XCD pair owns one 2MB B panel in L2
  int mb = ((s0 >> 3) << 1) | (xcd & 1);  // 0..63

  // expand-wave decomposition: 256 threads; thread owns rows (erow, erow+64), dim ad
  const int te = tid & 255;
  const int erow = te >> 2;            // 0..63
  const int ad = te & 3;
  const u32 aswz = (u32)(erow & 7);
  const u32 ak0 = (u32)(ad * 2);
  const float* xpa = x + (size_t)(mb * 128 + erow) * IN_DIM + ad;
  const float* xpb = xpa + (size_t)64 * IN_DIM;

  const char* bptr = Bp + (((size_t)(nb * 128) * 8 + wn * 4) * 2 + kt) * 1024 + (size_t)lane * 16;

  f32x4 acc[4][4];
#pragma unroll
  for (int i = 0; i < 4; ++i)
#pragma unroll
    for (int j = 0; j < 4; ++j) acc[i][j] = (f32x4){0.f, 0.f, 0.f, 0.f};

  u32x4 bA[4], bB[4];
  char* ab0 = smem;            // interval buffer 0 (even intervals)
  char* ab1 = smem + 65536;    // interval buffer 1 (odd intervals)

  float xc[8];                 // x values for interval iv+1 (expansion waves)
#pragma unroll
  for (int j = 0; j < 8; ++j) xc[j] = 0.f;

  if (isC) {
#pragma unroll
    for (int fn = 0; fn < 4; ++fn)
      bA[fn] = *(const u32x4*)(bptr + fn * 2048);
  } else {
    // prologue: expand interval 0 into ab0; preload x for interval 1
    float xi[8];
#pragma unroll
    for (int k = 0; k < 4; ++k) { xi[2 * k] = xpa[4 * k]; xi[2 * k + 1] = xpb[4 * k]; }
#pragma unroll
    for (int k = 0; k < 4; ++k) {
      expandA(xi[2 * k],     ab0 + k * 16384 + erow * 128, aswz, ak0);
      expandA(xi[2 * k + 1], ab0 + k * 16384 + (erow + 64) * 128, aswz, ak0);
    }
#pragma unroll
    for (int k = 0; k < 4; ++k) { xc[2 * k] = xpa[16 + 4 * k]; xc[2 * k + 1] = xpb[16 + 4 * k]; }
  }
  __syncthreads();   // one-time full drain (interval 0 visible)

  const u32 asl = (((u32)(kt * 4) | (u32)lkg) ^ (u32)(lrow & 7)) << 4;

#pragma unroll 1
  for (int iv = 0; iv < 32; ++iv) {
    if (isC) {
      const char* rb = (iv & 1) ? ab1 : ab0;
      const char* arb = rb + (wm * 64 + lrow) * 128;
      const int S = iv * 4;
      u32x4 af0[4], af1[4];
      // interval-top: frags for step 0
#pragma unroll
      for (int fm = 0; fm < 4; ++fm)
        af0[fm] = *(const u32x4*)(arb + fm * 2048 + asl);
      // k=0: prefetch step1 frags + B(S+1); MFMA step0
#pragma unroll
      for (int fm = 0; fm < 4; ++fm)
        af1[fm] = *(const u32x4*)(arb + 16384 + fm * 2048 + asl);
#pragma unroll
      for (int fn = 0; fn < 4; ++fn)
        bB[fn] = *(const u32x4*)(bptr + (size_t)(S + 1) * 16384 + fn * 2048);
      MM(af0, bA)
      // k=1: prefetch step2 frags + B(S+2); MFMA step1
#pragma unroll
      for (int fm = 0; fm < 4; ++fm)
        af0[fm] = *(const u32x4*)(arb + 2 * 16384 + fm * 2048 + asl);
#pragma unroll
      for (int fn = 0; fn < 4; ++fn)
        bA[fn] = *(const u32x4*)(bptr + (size_t)(S + 2) * 16384 + fn * 2048);
      MM(af1, bB)
      // k=2: prefetch step3 frags + B(S+3); MFMA step2
#pragma unroll
      for (int fm = 0; fm < 4; ++fm)
        af1[fm] = *(const u32x4*)(arb + 3 * 16384 + fm * 2048 + asl);
#pragma unroll
      for (int fn = 0; fn < 4; ++fn)
        bB[fn] = *(const u32x4*)(bptr + (size_t)(S + 3) * 16384 + fn * 2048);
      MM(af0, bA)
      // k=3: prefetch B(next interval step0); MFMA step3
      {
        int sn = (S + 4 < 128) ? (S + 4) : 127;
#pragma unroll
        for (int fn = 0; fn < 4; ++fn)
          bA[fn] = *(const u32x4*)(bptr + (size_t)sn * 16384 + fn * 2048);
      }
      MM(af1, bB)
    } else {
      // expansion: fill interval iv+1's buffer from xc (loaded last interval)
      if (iv + 1 < 32) {
        char* wb = (iv & 1) ? ab0 : ab1;
#pragma unroll
        for (int k = 0; k < 4; ++k) {
          expandA(xc[2 * k],     wb + k * 16384 + erow * 128, aswz, ak0);
          expandA(xc[2 * k + 1], wb + k * 16384 + (erow + 64) * 128, aswz, ak0);
        }
      }
      // load x for interval iv+2 (a full interval of latency cover)
      {
        int v2 = (iv + 2 < 32) ? (iv + 2) : 31;
        float xn[8];
#pragma unroll
        for (int k = 0; k < 4; ++k) {
          xn[2 * k]     = xpa[v2 * 16 + 4 * k];
          xn[2 * k + 1] = xpb[v2 * 16 + 4 * k];
        }
#pragma unroll
        for (int j = 0; j < 8; ++j) xc[j] = xn[j];
      }
      asm volatile("s_waitcnt lgkmcnt(0)" ::: "memory");
    }
    __builtin_amdgcn_s_barrier();
  }

  __syncthreads();  // full drain before smem reuse

  // epilogue: deterministic kt-reduction via LDS (stride 132 floats), +x
  float* red = (float*)smem;
  if (isC && kt == 1) {
#pragma unroll
    for (int fm = 0; fm < 4; ++fm)
#pragma unroll
      for (int fn = 0; fn < 4; ++fn) {
        int rr = wm * 64 + fm * 16 + lkg * 4;
        int cc = wn * 64 + fn * 16 + lrow;
#pragma unroll
        for (int r = 0; r < 4; ++r)
          red[(size_t)(rr + r) * 132 + cc] = acc[fm][fn][r];
      }
  }
  __syncthreads();
  if (isC && kt == 0) {
#pragma unroll
    for (int fm = 0; fm < 4; ++fm)
#pragma unroll
      for (int fn = 0; fn < 4; ++fn) {
        int rr = wm * 64 + fm * 16 + lkg * 4;
        int cc = wn * 64 + fn * 16 + lrow;
        size_t gb = (size_t)(mb * 128 + rr) * IN_DIM + nb * 128 + cc;
#pragma unroll
        for (int r = 0; r < 4; ++r) {
          size_t off = gb + (size_t)r * IN_DIM;
          out[off] = acc[fm][fn][r] + red[(size_t)(rr + r) * 132 + cc] + x[off];
        }
      }
  }
}

// ---------------------------------------------------------------------------
// Fallback (round-1 kernel) if ws too small for B_packed (8MB)
// ---------------------------------------------------------------------------
__device__ __forceinline__ void st_b16(char* rb, u32 swz, u32 k0, int c, u16 v) {
  u32 uc = (u32)c;
  u32 byte = (((k0 + (uc >> 3)) ^ swz) << 4) | ((uc & 7u) << 1);
  *(u16*)(rb + byte) = v;
}

__device__ __forceinline__ void stage_a_fb(char* aT, int row, int d, float xv) {
  char* rb = aT + row * 128;
  u32 swz = (u32)(row & 7);
  float xc = fminf(fmaxf(xv, -0.9999f), 0.9999f);
  float tp = __fmaf_rn(xc, 2.5f, 3.0f);
  float fj = floorf(tp);
  int jl = (int)fj;
  float u = tp - fj;
  float u2 = u * u, u3 = u2 * u;
  float vv = 1.0f - u;
  float b0 = vv * vv * vv * (1.0f / 6.0f);
  float b3 = u3 * (1.0f / 6.0f);
  float b1 = __fmaf_rn(0.5f, u3, __fmaf_rn(u2, -1.0f, 2.0f / 3.0f));
  float b2 = 1.0f - b0 - b1 - b3;
  float e = __expf(-xv);
  float sg = __fdividef(xv, 1.0f + e);
  u16 sh = f2bf(sg);
  float shf = __builtin_bit_cast(float, ((u32)sh) << 16);
  u16 slo = f2bf(sg - shf);
  u32 k0 = (u32)d * 2u;
  u32x4 z = {0u, 0u, 0u, 0u};
  *(u32x4*)(rb + ((k0 ^ swz) << 4)) = z;
  u32x4 z2 = {0u, 0u, ((u32)sh) << 16, (u32)slo};
  *(u32x4*)(rb + (((k0 + 1u) ^ swz) << 4)) = z2;
  st_b16(rb, swz, k0, jl + 2, f2bf(b0));
  st_b16(rb, swz, k0, jl + 3, f2bf(b1));
  st_b16(rb, swz, k0, jl + 4, f2bf(b2));
  st_b16(rb, swz, k0, jl + 5, f2bf(b3));
}

__launch_bounds__(512, 2)
__global__ void kan_fused(const float* __restrict__ x,
                          const float* __restrict__ coeffs,
                          const float* __restrict__ bw,
                          float* __restrict__ out) {
  __shared__ __align__(16) char smem[65536];
  const int tid = threadIdx.x;
  const int lane = tid & 63;
  const int wid = tid >> 6;
  const int team = wid >> 2;
  const int wm = (wid >> 1) & 1;
  const int wn = wid & 1;
  const int m0 = wm * 64, n0 = wn * 64;
  const int lrow = lane & 15;
  const int lkg = lane >> 4;
  int s = blockIdx.x;
  int xcd = s & 7;
  int nb = xcd >> 1;
  int mb = (s >> 3) | ((xcd & 1) << 5);
  const int t = tid & 255;
  const int arow = t >> 1;
  const int h = t & 1;
  char* aT = smem + team * 16384;
  char* bT = smem + 32768 + team * 16384;
  const int dim0 = team * 256;
  const float* xptr = x + (size_t)(mb * 128 + arow) * IN_DIM + dim0 + 2 * h;
  const float* cptr = coeffs + ((size_t)((nb * 128 + arow) * IN_DIM) + dim0) * 13 + 26 * h;
  const float* wptr = bw + (size_t)(nb * 128 + arow) * IN_DIM + dim0 + 2 * h;
  f32x4 acc[4][4];
#pragma unroll
  for (int i = 0; i < 4; ++i)
#pragma unroll
    for (int j = 0; j < 4; ++j) acc[i][j] = (f32x4){0.f, 0.f, 0.f, 0.f};
  float2 xv, wv;
  float2 cv0, cv1, cv2, cv3, cv4, cv5, cv6, cv7, cv8, cv9, cv10, cv11, cv12;
#define PREFETCH(STP)                                                     \
  {                                                                       \
    const float* cp_ = cptr + (STP) * 52;                                 \
    xv = *(const float2*)(xptr + (STP) * 4);                              \
    wv = *(const float2*)(wptr + (STP) * 4);                              \
    cv0 = *(const float2*)(cp_ + 0);   cv1 = *(const float2*)(cp_ + 2);   \
    cv2 = *(const float2*)(cp_ + 4);   cv3 = *(const float2*)(cp_ + 6);   \
    cv4 = *(const float2*)(cp_ + 8);   cv5 = *(const float2*)(cp_ + 10);  \
    cv6 = *(const float2*)(cp_ + 12);  cv7 = *(const float2*)(cp_ + 14);  \
    cv8 = *(const float2*)(cp_ + 16);  cv9 = *(const float2*)(cp_ + 18);  \
    cv10 = *(const float2*)(cp_ + 20); cv11 = *(const float2*)(cp_ + 22); \
    cv12 = *(const float2*)(cp_ + 24);                                    \
  }
  PREFETCH(0)
  for (int st = 0; st < 64; ++st) {
    stage_a_fb(aT, arow, 2 * h + 0, xv.x);
    stage_a_fb(aT, arow, 2 * h + 1, xv.y);
    {
      char* rb = bT + arow * 128;
      u32 swz = (u32)(arow & 7);
      u32 k0 = (u32)(2 * h) * 2u;
      u32x4 lo, hi;
      lo.x = pk2(cv0.x, cv0.y); lo.y = pk2(cv1.x, cv1.y);
      lo.z = pk2(cv2.x, cv2.y); lo.w = pk2(cv3.x, cv3.y);
      hi.x = pk2(cv4.x, cv4.y); hi.y = pk2(cv5.x, cv5.y);
      {
        u16 wb = f2bf(wv.x);
        hi.z = (u32)f2bf(cv6.x) | ((u32)wb << 16);
        hi.w = (u32)wb;
      }
      *(u32x4*)(rb + ((k0 ^ swz) << 4)) = lo;
      *(u32x4*)(rb + (((k0 + 1u) ^ swz) << 4)) = hi;
      lo.x = pk2(cv6.y, cv7.x);  lo.y = pk2(cv7.y, cv8.x);
      lo.z = pk2(cv8.y, cv9.x);  lo.w = pk2(cv9.y, cv10.x);
      hi.x = pk2(cv10.y, cv11.x); hi.y = pk2(cv11.y, cv12.x);
      {
        u16 wb = f2bf(wv.y);
        hi.z = (u32)f2bf(cv12.y) | ((u32)wb << 16);
        hi.w = (u32)wb;
      }
      *(u32x4*)(rb + (((k0 + 2u) ^ swz) << 4)) = lo;
      *(u32x4*)(rb + (((k0 + 3u) ^ swz) << 4)) = hi;
    }
    __syncthreads();
    if (st != 63) { PREFETCH(st + 1) }
    {
      const char* arb = aT + (m0 + lrow) * 128;
      const char* brb = bT + (n0 + lrow) * 128;
      u32 rsw = (u32)(lrow & 7);
#pragma unroll
      for (int ks = 0; ks < 2; ++ks) {
        u32 sl2 = (((u32)(ks * 4) | (u32)lkg) ^ rsw) << 4;
        bf16x8 af[4], bfr2[4];
#pragma unroll
        for (int fm = 0; fm < 4; ++fm)
          af[fm] = __builtin_bit_cast(bf16x8, *(const u32x4*)(arb + fm * 2048 + sl2));
#pragma unroll
        for (int fn = 0; fn < 4; ++fn)
          bfr2[fn] = __builtin_bit_cast(bf16x8, *(const u32x4*)(brb + fn * 2048 + sl2));
#pragma unroll
        for (int fm = 0; fm < 4; ++fm)
#pragma unroll
          for (int fn = 0; fn < 4; ++fn)
            acc[fm][fn] = __builtin_amdgcn_mfma_f32_16x16x32_bf16(
                af[fm], bfr2[fn], acc[fm][fn], 0, 0, 0);
      }
    }
    __syncthreads();
  }
  float* red = (float*)smem;
  if (team == 1) {
#pragma unroll
    for (int fm = 0; fm < 4; ++fm)
#pragma unroll
      for (int fn = 0; fn < 4; ++fn) {
        int rr = m0 + fm * 16 + lkg * 4;
        int cc = n0 + fn * 16 + lrow;
#pragma unroll
        for (int r = 0; r < 4; ++r) red[(rr + r) * 128 + cc] = acc[fm][fn][r];
      }
  }
  __syncthreads();
  if (team == 0) {
#pragma unroll
    for (int fm = 0; fm < 4; ++fm)
#pragma unroll
      for (int fn = 0; fn < 4; ++fn) {
        int rr = m0 + fm * 16 + lkg * 4;
        int ccol = n0 + fn * 16 + lrow;
        int grow = mb * 128 + rr;
        int gcol = nb * 128 + ccol;
#pragma unroll
        for (int r = 0; r < 4; ++r) {
          float v = acc[fm][fn][r] + red[(rr + r) * 128 + ccol] +
                    x[(size_t)(grow + r) * IN_DIM + gcol];
          out[(size_t)(grow + r) * IN_DIM + gcol] = v;
        }
      }
  }
}

extern "C" void kernel_launch(void* const* d_in, const int* in_sizes, int n_in,
                              void* d_out, int out_size, void* d_ws, size_t ws_size,
                              hipStream_t stream) {
  const float* x = (const float*)d_in[0];
  const float* coeffs = (const float*)d_in[1];
  const float* bw = (const float*)d_in[2];
  float* out = (float*)d_out;
  if (ws_size >= (size_t)512 * 16384) {  // 8 MB for B_packed
    char* Bp = (char*)d_ws;
    hipLaunchKernelGGL(pack_b, dim3(1024), dim3(256), 0, stream, coeffs, bw, Bp);
    hipLaunchKernelGGL(kan_gemm, dim3(256), dim3(768), 0, stream, x, Bp, out);
  } else {
    hipLaunchKernelGGL(kan_fused, dim3(256), dim3(512), 0, stream, x, coeffs, bw, out);
  }
}